// Round 8
// baseline (226.384 us; speedup 1.0000x reference)
//
#include <hip/hip_runtime.h>
#include <hip/hip_bf16.h>
#include <stdint.h>

#define LQ 1024
#define BQ 2
#define AQ 14
#define KQ 30
#define EFQ 128
#define EDGE_IN 3152
#define KPAD 3200
#define NCHUNK 50
#define ROWS (BQ*LQ*KQ)            /* 61440 */
#define EIDX_OFF (ROWS*EFQ)        /* 7864320 */

typedef __attribute__((ext_vector_type(8))) _Float16 half8;
typedef __attribute__((ext_vector_type(4))) float floatx4;
typedef unsigned long long ull;

static __device__ __forceinline__ uint32_t pkh(float a, float b) {
    auto h = __builtin_amdgcn_cvt_pkrtz(a, b);   // __fp16 ext_vector(2)
    return __builtin_bit_cast(uint32_t, h);
}

// ---------------------------------------------------------------------------
// Kernel A v4: one BLOCK per (b,i) row; 4 waves × 4 candidates/lane.
// Each wave: barrier-free top-30 of its 256 candidates (fp64 keys, (key,idx)
// lexicographic = ascending D, lower-index tie-break) -> sorted list in LDS.
// Thread 0 merges the 4 sorted lists. 8 blocks/CU = 32 waves/CU hides the
// butterfly latency that bounded v3.
// Fast path (mask all ones, block-uniform): keys = fp64 ssq (monotone with D).
// Slow path: exact fp64 replication incl. global lmax adjust.
// ---------------------------------------------------------------------------
__global__ __launch_bounds__(256) void topk_kernel(
    const float* __restrict__ X, const float* __restrict__ mask,
    float* __restrict__ out, int* __restrict__ idx_ws)
{
    __shared__ ull    klist[4][KQ];
    __shared__ int    ilist[4][KQ];
    __shared__ int    aflag[4];
    __shared__ double lmax_sh[4];

    const int t = threadIdx.x, w = t >> 6, lane = t & 63;
    const int row = blockIdx.x;                 // 0..2047
    const int b = row >> 10, i = row & (LQ - 1);

    size_t cb = ((size_t)(b*LQ + i))*42 + 3;    // CA of center
    const float mif = mask[b*LQ + i];
    const double cx = (double)X[cb], cy = (double)X[cb+1], cz = (double)X[cb+2];

    double Dk[4]; float mf[4];
    bool allone = (mif == 1.0f);
    #pragma unroll
    for (int s = 0; s < 4; ++s) {
        int j = w*256 + s*64 + lane;
        size_t base = ((size_t)(b*LQ + j))*42 + 3;
        double dx = __dsub_rn(cx, (double)X[base+0]);
        double dy = __dsub_rn(cy, (double)X[base+1]);
        double dz = __dsub_rn(cz, (double)X[base+2]);
        mf[s] = mask[b*LQ + j];
        Dk[s] = __dadd_rn(__dadd_rn(__dmul_rn(dx,dx), __dmul_rn(dy,dy)),
                          __dmul_rn(dz,dz));
        allone = allone && (mf[s] == 1.0f);
    }
    int aw = __all(allone ? 1 : 0);
    if (lane == 0) aflag[w] = aw;
    __syncthreads();
    const bool fast = aflag[0] && aflag[1] && aflag[2] && aflag[3];

    if (!fast) {
        // exact general path: D = mi*mj*sqrt(ssq+1e-6); key = D + 2(1-m2)*max(D)
        const double mi_d = (double)mif;
        double lm = 0.0;
        #pragma unroll
        for (int s = 0; s < 4; ++s) {
            double m2 = __dmul_rn(mi_d, (double)mf[s]);
            Dk[s] = __dmul_rn(m2, sqrt(__dadd_rn(Dk[s], 1e-6)));
            lm = fmax(lm, Dk[s]);
        }
        #pragma unroll
        for (int off = 32; off; off >>= 1) lm = fmax(lm, __shfl_xor(lm, off));
        if (lane == 0) lmax_sh[w] = lm;
        __syncthreads();
        double gl = fmax(fmax(lmax_sh[0], lmax_sh[1]), fmax(lmax_sh[2], lmax_sh[3]));
        #pragma unroll
        for (int s = 0; s < 4; ++s) {
            double m2 = __dmul_rn(mi_d, (double)mf[s]);
            Dk[s] = __dadd_rn(Dk[s],
                    __dmul_rn(__dmul_rn(2.0, __dsub_rn(1.0, m2)), gl));
        }
    }

    unsigned cons = 0;
    for (int k = 0; k < KQ; ++k) {
        ull bk = ~0ull; int bi = 1 << 30;
        #pragma unroll
        for (int s = 0; s < 4; ++s) {
            ull key = (ull)__double_as_longlong(Dk[s]);
            bool alive = !((cons >> s) & 1u);
            if (alive && key < bk) { bk = key; bi = w*256 + s*64 + lane; } // strict <: lowest s wins lane-internal ties
        }
        #pragma unroll
        for (int off = 32; off; off >>= 1) {
            ull okk = __shfl_xor(bk, off);
            int oii = __shfl_xor(bi, off);
            if (okk < bk || (okk == bk && oii < bi)) { bk = okk; bi = oii; }
        }
        if ((bi & 63) == lane) cons |= (1u << ((bi >> 6) & 3));
        if (lane == 0) { klist[w][k] = bk; ilist[w][k] = bi; }
    }
    __syncthreads();

    if (t == 0) {   // merge 4 sorted lists of 30 -> global top-30
        int ptr[4] = {0,0,0,0};
        ull hk[4]; int hi_[4];
        #pragma unroll
        for (int l = 0; l < 4; ++l) { hk[l] = klist[l][0]; hi_[l] = ilist[l][0]; }
        for (int k = 0; k < KQ; ++k) {
            int bsel = 0;
            #pragma unroll
            for (int l = 1; l < 4; ++l)
                if (hk[l] < hk[bsel] || (hk[l] == hk[bsel] && hi_[l] < hi_[bsel])) bsel = l;
            int rg = row*KQ + k;
            idx_ws[rg] = hi_[bsel];
            out[EIDX_OFF + rg] = (float)hi_[bsel];
            if (++ptr[bsel] < KQ) { hk[bsel] = klist[bsel][ptr[bsel]]; hi_[bsel] = ilist[bsel][ptr[bsel]]; }
            else hk[bsel] = ~0ull;
        }
    }
}

// ---------------------------------------------------------------------------
// Kernel C: pad W (128 x 3152 fp32) into ws as f16 (128 x 3200), zero pad.
// ---------------------------------------------------------------------------
__global__ __launch_bounds__(256) void wpad_kernel(
    const float* __restrict__ W, _Float16* __restrict__ wpad)
{
    int idx = blockIdx.x*256 + threadIdx.x;
    if (idx >= EFQ*KPAD) return;
    int n = idx / KPAD, f = idx - n*KPAD;
    float v = (f < EDGE_IN) ? W[(size_t)n*EDGE_IN + f] : 0.0f;
    wpad[idx] = (_Float16)v;
}

// ---------------------------------------------------------------------------
// Kernel B v4: fused feature-gen (f16, packed via cvt_pkrtz) + f16 MFMA GEMM,
// single-buffer async B staging (global_load_lds, XOR-swizzled) + LayerNorm.
// ---------------------------------------------------------------------------
struct FusedSmem {
    alignas(16) float atoms[128*42];           // 0..63 center rows, 64..127 neighbor
    alignas(16) unsigned short Bl[128*64];     // W chunk (f16 bits), row n stride 64, XOR-swizzled
    alignas(16) float drow[64];
    int residg[128];
    unsigned int maskb[128];
    float gsh[EFQ], bsh[EFQ];
};                                             // ~40.2 KB -> 4 blocks/CU

// Generate 8 contiguous features [f0, f0+8) for tile-local row m as 4 packed
// f16 dwords. RBF: exp(-((d - r*4/3)*0.8)^2) = exp2(-(u - r*v)^2),
// u = d*0.96089846, v = 1.28119795.
static __device__ __forceinline__ void gen8(
    const FusedSmem& sm, int m, int f0, uint32_t* __restrict__ v)
{
    if (f0 >= 16) {
        int p = (f0 - 16) >> 4;
        if (p >= AQ*AQ) { v[0] = v[1] = v[2] = v[3] = 0u; return; }
        int rbase = (f0 - 16) & 15;                 // 0 or 8
        int a  = (p * 74899) >> 20;                 // p / 14 for p < 2048
        int bp = p - a*14;
        bool czero = ((((sm.maskb[m] >> a) | (sm.maskb[64+m] >> bp)) & 1u) != 0u);
        const float* ca = &sm.atoms[m*42 + a*3];
        const float* na = &sm.atoms[(64+m)*42 + bp*3];
        float dx = ca[0]-na[0], dy = ca[1]-na[1], dz = ca[2]-na[2];
        float u = __builtin_amdgcn_sqrtf(dx*dx + dy*dy + dz*dz + 1e-6f) * 0.96089846f;
        float e[8];
        #pragma unroll
        for (int j = 0; j < 8; ++j) {
            float tt = __fmaf_rn(-(float)(rbase + j), 1.28119795f, u);
            e[j] = __builtin_amdgcn_exp2f(-(tt*tt));
        }
        #pragma unroll
        for (int k = 0; k < 4; ++k) v[k] = czero ? 0u : pkh(e[2*k], e[2*k+1]);
    } else {
        float d = sm.drow[m];
        const float fr[8] = {1.0f, 0.31622776601683794f, 0.1f,
            0.031622776601683794f, 0.01f, 0.0031622776601683794f,
            0.001f, 0.00031622776601683794f};
        float e[8];
        if (f0 == 0) {
            #pragma unroll
            for (int j = 0; j < 8; ++j) e[j] = __cosf(d * fr[j]);
        } else {
            #pragma unroll
            for (int j = 0; j < 8; ++j) e[j] = __sinf(d * fr[j]);
        }
        #pragma unroll
        for (int k = 0; k < 4; ++k) v[k] = pkh(e[2*k], e[2*k+1]);
    }
}

__global__ __launch_bounds__(256) void fused_kernel(
    const float* __restrict__ X, const float* __restrict__ atom_mask,
    const _Float16* __restrict__ wpad, const float* __restrict__ gamma,
    const float* __restrict__ beta, const int* __restrict__ idx_ws,
    float* __restrict__ out)
{
    __shared__ FusedSmem sm;
    const int t = threadIdx.x;
    const int row0 = blockIdx.x * 64;
    const int b = row0 / (LQ*KQ);            // tiles never straddle b (30720 % 64 == 0)

    if (t < 64) {
        int rg = row0 + t;
        int rem = rg - b*(LQ*KQ);
        int i = rem / KQ;
        int j = idx_ws[rg];
        sm.residg[t]    = b*LQ + i;
        sm.residg[64+t] = b*LQ + j;
        sm.drow[t] = (float)j - (float)i;
    }
    if (t < EFQ) { sm.gsh[t] = gamma[t]; sm.bsh[t] = beta[t]; }
    __syncthreads();

    for (int u = t; u < 128*42; u += 256) {  // 21 exact iterations
        int s = u / 42; int e = u - s*42;
        sm.atoms[s*42 + e] = X[(size_t)sm.residg[s]*42 + e];
    }
    __syncthreads();

    if (t < 128) {
        float* at = &sm.atoms[t*42];
        float Nx=at[0],Ny=at[1],Nz=at[2], Cax=at[3],Cay=at[4],Caz=at[5],
              Cx=at[6],Cy=at[7],Cz=at[8];
        float bx=Cax-Nx, by=Cay-Ny, bz=Caz-Nz;
        float ex=Cx-Cax, ey=Cy-Cay, ez=Cz-Caz;
        float ax = by*ez - bz*ey, ay = bz*ex - bx*ez, az = bx*ey - by*ex;
        at[12] = -0.58273431f*ax + 0.56802827f*bx - 0.54067466f*ex + Cax;  // Cb
        at[13] = -0.58273431f*ay + 0.56802827f*by - 0.54067466f*ey + Cay;
        at[14] = -0.58273431f*az + 0.56802827f*bz - 0.54067466f*ez + Caz;
        unsigned mb = 0;
        const float* amp = &atom_mask[(size_t)sm.residg[t]*AQ];
        #pragma unroll
        for (int a = 0; a < AQ; ++a) if (amp[a] > 0.5f) mb |= (1u << a);
        sm.maskb[t] = mb;
    }

    const int w = t >> 6, lane = t & 63, q = lane >> 4, l15 = lane & 15;
    const int m = w*16 + l15;                 // tile-local row this thread's A-frag covers

    // Async B staging: lane-contiguous LDS (global_load_lds constraint), XOR
    // swizzle on the SOURCE k-block: LDS slot (n, s) holds k-block s ^ (n&7).
    auto stage = [&](int c) {
        #pragma unroll
        for (int i2 = 0; i2 < 4; ++i2) {
            int region = w*4 + i2;                        // 8 rows per region
            int n = region*8 + (lane >> 3);
            int kbsrc = (lane & 7) ^ (lane >> 3);         // (slot) ^ (n&7)
            const _Float16* g = wpad + (size_t)n*KPAD + c*64 + kbsrc*8;
            __builtin_amdgcn_global_load_lds(
                (const __attribute__((address_space(1))) uint32_t*)g,
                (__attribute__((address_space(3))) uint32_t*)&sm.Bl[region*512],
                16, 0, 0);
        }
    };

    floatx4 acc[8];
    #pragma unroll
    for (int nt = 0; nt < 8; ++nt) acc[nt] = (floatx4){0.f,0.f,0.f,0.f};

    __syncthreads();                          // atoms/maskb ready

    union H8 { uint32_t u[4]; half8 h; };
    for (int c = 0; c < NCHUNK; ++c) {
        if (c) __syncthreads();               // all reads of previous B chunk done
        stage(c);                             // async global->LDS, in flight during gen
        H8 va0, va1;
        gen8(sm, m, c*64 + q*8,      va0.u);
        gen8(sm, m, c*64 + 32 + q*8, va1.u);
        __syncthreads();                      // drains vmcnt: Bl ready
        #pragma unroll
        for (int nt = 0; nt < 8; ++nt) {
            int n = nt*16 + l15;
            half8 b0 = *reinterpret_cast<const half8*>(
                &sm.Bl[n*64 + ((q ^ (n&7))*8)]);
            half8 b1 = *reinterpret_cast<const half8*>(
                &sm.Bl[n*64 + (((4+q) ^ (n&7))*8)]);
            acc[nt] = __builtin_amdgcn_mfma_f32_16x16x32_f16(va0.h, b0, acc[nt], 0, 0, 0);
            acc[nt] = __builtin_amdgcn_mfma_f32_16x16x32_f16(va1.h, b1, acc[nt], 0, 0, 0);
        }
    }

    // LayerNorm epilogue. C/D layout: col = lane&15, row = quad*4 + reg.
    #pragma unroll
    for (int v = 0; v < 4; ++v) {
        float s = 0.f, s2 = 0.f;
        #pragma unroll
        for (int nt = 0; nt < 8; ++nt) { float x = acc[nt][v]; s += x; s2 += x*x; }
        #pragma unroll
        for (int off = 1; off < 16; off <<= 1) {
            s  += __shfl_xor(s,  off);
            s2 += __shfl_xor(s2, off);
        }
        float mean = s * (1.0f/128.0f);
        float var  = s2 * (1.0f/128.0f) - mean*mean;
        float rstd = 1.0f / sqrtf(var + 1e-5f);
        int row_l = w*16 + q*4 + v;
        size_t obase = (size_t)(row0 + row_l)*EFQ;
        #pragma unroll
        for (int nt = 0; nt < 8; ++nt) {
            int col = nt*16 + l15;
            out[obase + col] = (acc[nt][v] - mean)*rstd*sm.gsh[col] + sm.bsh[col];
        }
    }
}

extern "C" void kernel_launch(void* const* d_in, const int* in_sizes, int n_in,
                              void* d_out, int out_size, void* d_ws, size_t ws_size,
                              hipStream_t stream)
{
    const float* X         = (const float*)d_in[0];
    const float* mask      = (const float*)d_in[1];
    // d_in[2] residue_idx, d_in[3] chain_labels: unused by the reference math
    const float* atom_mask = (const float*)d_in[4];
    const float* W         = (const float*)d_in[5];
    const float* gamma     = (const float*)d_in[6];
    const float* beta      = (const float*)d_in[7];
    float* out = (float*)d_out;

    int*       idx_ws = (int*)d_ws;                               // 61440*4 B
    _Float16*  wpad   = (_Float16*)((char*)d_ws + 262144);        // 128*3200*2 B

    hipLaunchKernelGGL(wpad_kernel, dim3((EFQ*KPAD + 255)/256), dim3(256), 0, stream,
                       W, wpad);
    hipLaunchKernelGGL(topk_kernel, dim3(BQ*LQ), dim3(256), 0, stream,
                       X, mask, out, idx_ws);
    hipLaunchKernelGGL(fused_kernel, dim3(ROWS/64), dim3(256), 0, stream,
                       X, atom_mask, wpad, gamma, beta, idx_ws, out);
}

// Round 9
// 189.756 us; speedup vs baseline: 1.1930x; 1.1930x over previous
//
#include <hip/hip_runtime.h>
#include <hip/hip_bf16.h>
#include <stdint.h>

#define LQ 1024
#define BQ 2
#define AQ 14
#define KQ 30
#define EFQ 128
#define EDGE_IN 3152
#define KPAD 3200
#define NCHUNK 50
#define ROWS (BQ*LQ*KQ)            /* 61440 */
#define EIDX_OFF (ROWS*EFQ)        /* 7864320 */

typedef __attribute__((ext_vector_type(8))) _Float16 half8;
typedef __attribute__((ext_vector_type(4))) float floatx4;
typedef unsigned long long ull;

static __device__ __forceinline__ uint32_t pkh(float a, float b) {
    auto h = __builtin_amdgcn_cvt_pkrtz(a, b);   // __fp16 ext_vector(2)
    return __builtin_bit_cast(uint32_t, h);
}

// ---------------------------------------------------------------------------
// Kernel A v5: 8 rows per block (512 thr), ONE WAVE PER ROW (v3's verified
// selection loop, byte-identical semantics), with block-cooperative LDS
// staging of the 1024 CA coords + mask (coalesced once, instead of every
// wave re-gathering 168B-strided global). fp32 bits pass through LDS
// unchanged -> fp64 key math identical -> exact vs float64 numpy reference.
// ---------------------------------------------------------------------------
__global__ __launch_bounds__(512) void topk_kernel(
    const float* __restrict__ X, const float* __restrict__ mask,
    float* __restrict__ out, int* __restrict__ idx_ws)
{
    __shared__ float xs[LQ], ys[LQ], zs[LQ], ms[LQ];

    const int t = threadIdx.x, w = t >> 6, lane = t & 63;
    const int row = blockIdx.x*8 + w;           // 256 blocks x 8 rows; same b per block
    const int b = row >> 10, i = row & (LQ - 1);

    for (int j = t; j < LQ; j += 512) {
        size_t base = ((size_t)(b*LQ + j))*42 + 3;   // atom 1 (CA)
        xs[j] = X[base+0]; ys[j] = X[base+1]; zs[j] = X[base+2];
        ms[j] = mask[b*LQ + j];
    }
    __syncthreads();

    const float mif = ms[i];
    const double cx = (double)xs[i], cy = (double)ys[i], cz = (double)zs[i];

    double Dk[16]; float mf[16];
    bool allone = (mif == 1.0f);
    #pragma unroll
    for (int s = 0; s < 16; ++s) {
        int j = s*64 + lane;
        double dx = __dsub_rn(cx, (double)xs[j]);
        double dy = __dsub_rn(cy, (double)ys[j]);
        double dz = __dsub_rn(cz, (double)zs[j]);
        mf[s] = ms[j];
        Dk[s] = __dadd_rn(__dadd_rn(__dmul_rn(dx,dx), __dmul_rn(dy,dy)),
                          __dmul_rn(dz,dz));
        allone = allone && (mf[s] == 1.0f);
    }

    if (!__all(allone ? 1 : 0)) {
        // exact general path: D = mi*mj*sqrt(ssq+1e-6); key = D + 2(1-m2)*max(D)
        const double mi_d = (double)mif;
        double lm = 0.0;
        #pragma unroll
        for (int s = 0; s < 16; ++s) {
            double m2 = __dmul_rn(mi_d, (double)mf[s]);
            Dk[s] = __dmul_rn(m2, sqrt(__dadd_rn(Dk[s], 1e-6)));
            lm = fmax(lm, Dk[s]);
        }
        #pragma unroll
        for (int off = 32; off; off >>= 1) lm = fmax(lm, __shfl_xor(lm, off));
        #pragma unroll
        for (int s = 0; s < 16; ++s) {
            double m2 = __dmul_rn(mi_d, (double)mf[s]);
            Dk[s] = __dadd_rn(Dk[s],
                    __dmul_rn(__dmul_rn(2.0, __dsub_rn(1.0, m2)), lm));
        }
    }
    // fast path: keys = fp64 ssq (positive; bit pattern monotone, ordering
    // identical to D = sqrt(ssq+1e-6) since the map is strictly monotone)

    unsigned cons = 0;
    for (int k = 0; k < KQ; ++k) {
        ull bk = ~0ull; int bi = 1 << 30;
        #pragma unroll
        for (int s = 0; s < 16; ++s) {
            ull key = (ull)__double_as_longlong(Dk[s]);
            bool alive = !((cons >> s) & 1u);
            if (alive && key < bk) { bk = key; bi = s*64 + lane; }  // strict <: lowest s wins lane-internal ties
        }
        #pragma unroll
        for (int off = 32; off; off >>= 1) {
            ull okk = __shfl_xor(bk, off);
            int oii = __shfl_xor(bi, off);
            if (okk < bk || (okk == bk && oii < bi)) { bk = okk; bi = oii; }
        }
        if ((bi & 63) == lane) cons |= (1u << (bi >> 6));
        if (lane == 0) {
            int rg = row*KQ + k;
            idx_ws[rg] = bi;
            out[EIDX_OFF + rg] = (float)bi;
        }
    }
}

// ---------------------------------------------------------------------------
// Kernel C: pad W (128 x 3152 fp32) into ws as f16 (128 x 3200), zero pad.
// ---------------------------------------------------------------------------
__global__ __launch_bounds__(256) void wpad_kernel(
    const float* __restrict__ W, _Float16* __restrict__ wpad)
{
    int idx = blockIdx.x*256 + threadIdx.x;
    if (idx >= EFQ*KPAD) return;
    int n = idx / KPAD, f = idx - n*KPAD;
    float v = (f < EDGE_IN) ? W[(size_t)n*EDGE_IN + f] : 0.0f;
    wpad[idx] = (_Float16)v;
}

// ---------------------------------------------------------------------------
// Kernel B v5: fused feature-gen (f16 packed) + f16 MFMA GEMM + LayerNorm.
// All loop-invariant address math hoisted out of the 50-chunk K-loop.
// ---------------------------------------------------------------------------
struct FusedSmem {
    alignas(16) float atoms[128*42];           // 0..63 center rows, 64..127 neighbor
    alignas(16) unsigned short Bl[128*64];     // W chunk (f16 bits), row n stride 64, XOR-swizzled
    alignas(16) float drow[64];
    int residg[128];
    unsigned int maskb[128];
    float gsh[EFQ], bsh[EFQ];
};                                             // ~40.2 KB -> 3 blocks/CU

// Generate 8 contiguous features [f0, f0+8) for tile-local row m as 4 packed
// f16 dwords. RBF: exp(-((d - r*4/3)*0.8)^2) = exp2(-(u - r*v)^2),
// u = d*0.96089846, v = 1.28119795. All row-invariant operands hoisted.
static __device__ __forceinline__ void gen8(
    const float* __restrict__ atomsA, const float* __restrict__ atomsB,
    unsigned maskA, unsigned maskB, float drowv,
    int f0, uint32_t* __restrict__ v)
{
    if (f0 >= 16) {
        int p = (f0 - 16) >> 4;
        if (p >= AQ*AQ) { v[0] = v[1] = v[2] = v[3] = 0u; return; }
        int rbase = (f0 - 16) & 15;                 // 0 or 8
        int a  = (p * 74899) >> 20;                 // p / 14 for p < 2048
        int bp = p - a*14;
        bool czero = ((((maskA >> a) | (maskB >> bp)) & 1u) != 0u);
        const float* ca = atomsA + a*3;
        const float* na = atomsB + bp*3;
        float dx = ca[0]-na[0], dy = ca[1]-na[1], dz = ca[2]-na[2];
        float u = __builtin_amdgcn_sqrtf(dx*dx + dy*dy + dz*dz + 1e-6f) * 0.96089846f;
        float e[8];
        #pragma unroll
        for (int j = 0; j < 8; ++j) {
            float tt = __fmaf_rn(-(float)(rbase + j), 1.28119795f, u);
            e[j] = __builtin_amdgcn_exp2f(-(tt*tt));
        }
        #pragma unroll
        for (int k = 0; k < 4; ++k) v[k] = czero ? 0u : pkh(e[2*k], e[2*k+1]);
    } else {
        const float fr[8] = {1.0f, 0.31622776601683794f, 0.1f,
            0.031622776601683794f, 0.01f, 0.0031622776601683794f,
            0.001f, 0.00031622776601683794f};
        float e[8];
        if (f0 == 0) {
            #pragma unroll
            for (int j = 0; j < 8; ++j) e[j] = __cosf(drowv * fr[j]);
        } else {
            #pragma unroll
            for (int j = 0; j < 8; ++j) e[j] = __sinf(drowv * fr[j]);
        }
        #pragma unroll
        for (int k = 0; k < 4; ++k) v[k] = pkh(e[2*k], e[2*k+1]);
    }
}

__global__ __launch_bounds__(256) void fused_kernel(
    const float* __restrict__ X, const float* __restrict__ atom_mask,
    const _Float16* __restrict__ wpad, const float* __restrict__ gamma,
    const float* __restrict__ beta, const int* __restrict__ idx_ws,
    float* __restrict__ out)
{
    __shared__ FusedSmem sm;
    const int t = threadIdx.x;
    const int row0 = blockIdx.x * 64;
    const int b = row0 / (LQ*KQ);            // tiles never straddle b (30720 % 64 == 0)

    if (t < 64) {
        int rg = row0 + t;
        int rem = rg - b*(LQ*KQ);
        int i = rem / KQ;
        int j = idx_ws[rg];
        sm.residg[t]    = b*LQ + i;
        sm.residg[64+t] = b*LQ + j;
        sm.drow[t] = (float)j - (float)i;
    }
    if (t < EFQ) { sm.gsh[t] = gamma[t]; sm.bsh[t] = beta[t]; }
    __syncthreads();

    for (int u = t; u < 128*42; u += 256) {  // 21 exact iterations
        int s = u / 42; int e = u - s*42;
        sm.atoms[s*42 + e] = X[(size_t)sm.residg[s]*42 + e];
    }
    __syncthreads();

    if (t < 128) {
        float* at = &sm.atoms[t*42];
        float Nx=at[0],Ny=at[1],Nz=at[2], Cax=at[3],Cay=at[4],Caz=at[5],
              Cx=at[6],Cy=at[7],Cz=at[8];
        float bx=Cax-Nx, by=Cay-Ny, bz=Caz-Nz;
        float ex=Cx-Cax, ey=Cy-Cay, ez=Cz-Caz;
        float ax = by*ez - bz*ey, ay = bz*ex - bx*ez, az = bx*ey - by*ex;
        at[12] = -0.58273431f*ax + 0.56802827f*bx - 0.54067466f*ex + Cax;  // Cb
        at[13] = -0.58273431f*ay + 0.56802827f*by - 0.54067466f*ey + Cay;
        at[14] = -0.58273431f*az + 0.56802827f*bz - 0.54067466f*ez + Caz;
        unsigned mb = 0;
        const float* amp = &atom_mask[(size_t)sm.residg[t]*AQ];
        #pragma unroll
        for (int a = 0; a < AQ; ++a) if (amp[a] > 0.5f) mb |= (1u << a);
        sm.maskb[t] = mb;
    }

    const int w = t >> 6, lane = t & 63, q = lane >> 4, l15 = lane & 15;
    const int m = w*16 + l15;                 // tile-local row this thread's A-frag covers

    // ---- loop-invariant hoists -------------------------------------------
    int boff0[8], boff1[8];                   // B-frag LDS offsets (XOR swizzle)
    #pragma unroll
    for (int nt = 0; nt < 8; ++nt) {
        int n = nt*16 + l15;
        boff0[nt] = n*64 + ((q ^ (n&7))*8);
        boff1[nt] = n*64 + (((4+q) ^ (n&7))*8);
    }
    // stage(): per-i2 invariant parts
    int stRegion[4]; const _Float16* stBase[4];
    #pragma unroll
    for (int i2 = 0; i2 < 4; ++i2) {
        int region = w*4 + i2;
        int n = region*8 + (lane >> 3);
        int kbsrc = (lane & 7) ^ (lane >> 3);
        stRegion[i2] = region;
        stBase[i2] = wpad + (size_t)n*KPAD + kbsrc*8;
    }
    auto stage = [&](int c) {
        #pragma unroll
        for (int i2 = 0; i2 < 4; ++i2) {
            const _Float16* g = stBase[i2] + c*64;
            __builtin_amdgcn_global_load_lds(
                (const __attribute__((address_space(1))) uint32_t*)g,
                (__attribute__((address_space(3))) uint32_t*)&sm.Bl[stRegion[i2]*512],
                16, 0, 0);
        }
    };

    floatx4 acc[8];
    #pragma unroll
    for (int nt = 0; nt < 8; ++nt) acc[nt] = (floatx4){0.f,0.f,0.f,0.f};

    __syncthreads();                          // atoms/maskb ready

    const float* atomsA = &sm.atoms[m*42];
    const float* atomsB = &sm.atoms[(64+m)*42];
    const unsigned maskA = sm.maskb[m], maskB = sm.maskb[64+m];
    const float drowv = sm.drow[m];

    union H8 { uint32_t u[4]; half8 h; };
    for (int c = 0; c < NCHUNK; ++c) {
        if (c) __syncthreads();               // all reads of previous B chunk done
        stage(c);                             // async global->LDS, in flight during gen
        H8 va0, va1;
        gen8(atomsA, atomsB, maskA, maskB, drowv, c*64 + q*8,      va0.u);
        gen8(atomsA, atomsB, maskA, maskB, drowv, c*64 + 32 + q*8, va1.u);
        __syncthreads();                      // drains vmcnt: Bl ready
        #pragma unroll
        for (int nt = 0; nt < 8; ++nt) {
            half8 b0 = *reinterpret_cast<const half8*>(&sm.Bl[boff0[nt]]);
            half8 b1 = *reinterpret_cast<const half8*>(&sm.Bl[boff1[nt]]);
            acc[nt] = __builtin_amdgcn_mfma_f32_16x16x32_f16(va0.h, b0, acc[nt], 0, 0, 0);
            acc[nt] = __builtin_amdgcn_mfma_f32_16x16x32_f16(va1.h, b1, acc[nt], 0, 0, 0);
        }
    }

    // LayerNorm epilogue. C/D layout: col = lane&15, row = quad*4 + reg.
    #pragma unroll
    for (int v = 0; v < 4; ++v) {
        float s = 0.f, s2 = 0.f;
        #pragma unroll
        for (int nt = 0; nt < 8; ++nt) { float x = acc[nt][v]; s += x; s2 += x*x; }
        #pragma unroll
        for (int off = 1; off < 16; off <<= 1) {
            s  += __shfl_xor(s,  off);
            s2 += __shfl_xor(s2, off);
        }
        float mean = s * (1.0f/128.0f);
        float var  = s2 * (1.0f/128.0f) - mean*mean;
        float rstd = 1.0f / sqrtf(var + 1e-5f);
        int row_l = w*16 + q*4 + v;
        size_t obase = (size_t)(row0 + row_l)*EFQ;
        #pragma unroll
        for (int nt = 0; nt < 8; ++nt) {
            int col = nt*16 + l15;
            out[obase + col] = (acc[nt][v] - mean)*rstd*sm.gsh[col] + sm.bsh[col];
        }
    }
}

extern "C" void kernel_launch(void* const* d_in, const int* in_sizes, int n_in,
                              void* d_out, int out_size, void* d_ws, size_t ws_size,
                              hipStream_t stream)
{
    const float* X         = (const float*)d_in[0];
    const float* mask      = (const float*)d_in[1];
    // d_in[2] residue_idx, d_in[3] chain_labels: unused by the reference math
    const float* atom_mask = (const float*)d_in[4];
    const float* W         = (const float*)d_in[5];
    const float* gamma     = (const float*)d_in[6];
    const float* beta      = (const float*)d_in[7];
    float* out = (float*)d_out;

    int*       idx_ws = (int*)d_ws;                               // 61440*4 B
    _Float16*  wpad   = (_Float16*)((char*)d_ws + 262144);        // 128*3200*2 B

    hipLaunchKernelGGL(wpad_kernel, dim3((EFQ*KPAD + 255)/256), dim3(256), 0, stream,
                       W, wpad);
    hipLaunchKernelGGL(topk_kernel, dim3(BQ*LQ/8), dim3(512), 0, stream,
                       X, mask, out, idx_ws);
    hipLaunchKernelGGL(fused_kernel, dim3(ROWS/64), dim3(256), 0, stream,
                       X, atom_mask, wpad, gamma, beta, idx_ws, out);
}

// Round 10
// 176.214 us; speedup vs baseline: 1.2847x; 1.0769x over previous
//
#include <hip/hip_runtime.h>
#include <hip/hip_bf16.h>
#include <stdint.h>

#define LQ 1024
#define BQ 2
#define AQ 14
#define KQ 30
#define EFQ 128
#define EDGE_IN 3152
#define KPAD 3200
#define NCHUNK 50
#define MTILE 128
#define ROWS (BQ*LQ*KQ)            /* 61440 */
#define EIDX_OFF (ROWS*EFQ)        /* 7864320 */

typedef __attribute__((ext_vector_type(8))) _Float16 half8;
typedef __attribute__((ext_vector_type(4))) float floatx4;
typedef unsigned long long ull;

static __device__ __forceinline__ uint32_t pkh(float a, float b) {
    auto h = __builtin_amdgcn_cvt_pkrtz(a, b);   // __fp16 ext_vector(2)
    return __builtin_bit_cast(uint32_t, h);
}
static __device__ __forceinline__ ull umin64(ull a, ull b) { return a < b ? a : b; }

// ---------------------------------------------------------------------------
// Kernel A v6: blocks 0..255: topk (8 rows/block, one wave per row);
// blocks 256..305: W fp32 -> f16 padded copy (merged wpad).
// Selection keys: fp64 ssq (fast path; monotone with D when mask all ones) or
// exact fp64 D_adjust (slow path), with the candidate index PACKED into the
// low 10 bits ((bits & ~1023) | j): u64 order == (key, idx) lex order ==
// ascending D with lower-index tie-break (truncation collision prob ~5e-7 on
// 42 mantissa bits). Tournament = plain u64 min: 15-op min-tree + 6-step
// butterfly; removal = overwrite with MAX. ~3x shorter serial chain than v5.
// ---------------------------------------------------------------------------
__global__ __launch_bounds__(512) void topk_kernel(
    const float* __restrict__ X, const float* __restrict__ mask,
    const float* __restrict__ W, float* __restrict__ out,
    int* __restrict__ idx_ws, _Float16* __restrict__ wpad)
{
    __shared__ float xs[LQ], ys[LQ], zs[LQ], ms[LQ];
    const int t = threadIdx.x;

    if (blockIdx.x >= 256) {                    // ---- merged wpad ----
        int base = (blockIdx.x - 256)*8192 + t; // 50 blocks x 8192 = 409600 exact
        #pragma unroll
        for (int r = 0; r < 16; ++r) {
            int idx = base + r*512;
            int n = idx / KPAD, f = idx - n*KPAD;
            float v = (f < EDGE_IN) ? W[(size_t)n*EDGE_IN + f] : 0.0f;
            wpad[idx] = (_Float16)v;
        }
        return;
    }

    const int w = t >> 6, lane = t & 63;
    const int row = blockIdx.x*8 + w;           // same b for whole block
    const int b = row >> 10, i = row & (LQ - 1);

    for (int j = t; j < LQ; j += 512) {
        size_t base = ((size_t)(b*LQ + j))*42 + 3;   // atom 1 (CA)
        xs[j] = X[base+0]; ys[j] = X[base+1]; zs[j] = X[base+2];
        ms[j] = mask[b*LQ + j];
    }
    __syncthreads();

    const float mif = ms[i];
    const double cx = (double)xs[i], cy = (double)ys[i], cz = (double)zs[i];

    double Dk[16]; float mf[16];
    bool allone = (mif == 1.0f);
    #pragma unroll
    for (int s = 0; s < 16; ++s) {
        int j = s*64 + lane;
        double dx = __dsub_rn(cx, (double)xs[j]);
        double dy = __dsub_rn(cy, (double)ys[j]);
        double dz = __dsub_rn(cz, (double)zs[j]);
        mf[s] = ms[j];
        Dk[s] = __dadd_rn(__dadd_rn(__dmul_rn(dx,dx), __dmul_rn(dy,dy)),
                          __dmul_rn(dz,dz));
        allone = allone && (mf[s] == 1.0f);
    }

    if (!__all(allone ? 1 : 0)) {
        // exact general path: D = mi*mj*sqrt(ssq+1e-6); key = D + 2(1-m2)*max(D)
        const double mi_d = (double)mif;
        double lm = 0.0;
        #pragma unroll
        for (int s = 0; s < 16; ++s) {
            double m2 = __dmul_rn(mi_d, (double)mf[s]);
            Dk[s] = __dmul_rn(m2, sqrt(__dadd_rn(Dk[s], 1e-6)));
            lm = fmax(lm, Dk[s]);
        }
        #pragma unroll
        for (int off = 32; off; off >>= 1) lm = fmax(lm, __shfl_xor(lm, off));
        #pragma unroll
        for (int s = 0; s < 16; ++s) {
            double m2 = __dmul_rn(mi_d, (double)mf[s]);
            Dk[s] = __dadd_rn(Dk[s],
                    __dmul_rn(__dmul_rn(2.0, __dsub_rn(1.0, m2)), lm));
        }
    }

    ull key[16];
    #pragma unroll
    for (int s = 0; s < 16; ++s)
        key[s] = (((ull)__double_as_longlong(Dk[s])) & ~1023ull)
               | (unsigned)(s*64 + lane);

    for (int k = 0; k < KQ; ++k) {
        // balanced min-tree over 16 local candidates
        ull a0 = umin64(key[0],  key[1]),  a1 = umin64(key[2],  key[3]);
        ull a2 = umin64(key[4],  key[5]),  a3 = umin64(key[6],  key[7]);
        ull a4 = umin64(key[8],  key[9]),  a5 = umin64(key[10], key[11]);
        ull a6 = umin64(key[12], key[13]), a7 = umin64(key[14], key[15]);
        ull b0 = umin64(a0, a1), b1 = umin64(a2, a3);
        ull b2 = umin64(a4, a5), b3 = umin64(a6, a7);
        ull bk = umin64(umin64(b0, b1), umin64(b2, b3));
        #pragma unroll
        for (int off = 32; off; off >>= 1)
            bk = umin64(bk, (ull)__shfl_xor(bk, off));
        int j = (int)(bk & 1023ull);
        if (lane == 0) {
            int rg = row*KQ + k;
            idx_ws[rg] = j;
            out[EIDX_OFF + rg] = (float)j;
        }
        // remove winner: its owner lane MAXes the slot
        bool mine = ((j & 63) == lane);
        int s_win = j >> 6;
        #pragma unroll
        for (int s = 0; s < 16; ++s)
            key[s] = (mine && s == s_win) ? ~0ull : key[s];
    }
}

// ---------------------------------------------------------------------------
// Kernel B v6: fused feature-gen (f16 packed) + f16 MFMA GEMM + LayerNorm.
// M-tile 128 (512 thr / 8 waves), LDS ~63 KB -> 2 blocks/CU = 16 waves/CU.
// ---------------------------------------------------------------------------
struct FusedSmem {
    alignas(16) float atoms[256*42];           // 0..127 center, 128..255 neighbor
    alignas(16) unsigned short Bl[128*64];     // W chunk (f16 bits), XOR-swizzled
    alignas(16) float drow[MTILE];
    int residg[256];
    unsigned int maskb[256];
    float gsh[EFQ], bsh[EFQ];
};                                             // 62,976 B

// Generate 8 contiguous features [f0, f0+8) for tile-local row m as 4 packed
// f16 dwords. RBF: exp(-((d - r*4/3)*0.8)^2) = exp2(-(u - r*v)^2),
// u = d*0.96089846, v = 1.28119795.
static __device__ __forceinline__ void gen8(
    const float* __restrict__ atomsA, const float* __restrict__ atomsB,
    unsigned maskA, unsigned maskB, float drowv,
    int f0, uint32_t* __restrict__ v)
{
    if (f0 >= 16) {
        int p = (f0 - 16) >> 4;
        if (p >= AQ*AQ) { v[0] = v[1] = v[2] = v[3] = 0u; return; }
        int rbase = (f0 - 16) & 15;                 // 0 or 8
        int a  = (p * 74899) >> 20;                 // p / 14 for p < 2048
        int bp = p - a*14;
        bool czero = ((((maskA >> a) | (maskB >> bp)) & 1u) != 0u);
        const float* ca = atomsA + a*3;
        const float* na = atomsB + bp*3;
        float dx = ca[0]-na[0], dy = ca[1]-na[1], dz = ca[2]-na[2];
        float u = __builtin_amdgcn_sqrtf(dx*dx + dy*dy + dz*dz + 1e-6f) * 0.96089846f;
        float e[8];
        #pragma unroll
        for (int j = 0; j < 8; ++j) {
            float tt = __fmaf_rn(-(float)(rbase + j), 1.28119795f, u);
            e[j] = __builtin_amdgcn_exp2f(-(tt*tt));
        }
        #pragma unroll
        for (int k = 0; k < 4; ++k) v[k] = czero ? 0u : pkh(e[2*k], e[2*k+1]);
    } else {
        const float fr[8] = {1.0f, 0.31622776601683794f, 0.1f,
            0.031622776601683794f, 0.01f, 0.0031622776601683794f,
            0.001f, 0.00031622776601683794f};
        float e[8];
        if (f0 == 0) {
            #pragma unroll
            for (int j = 0; j < 8; ++j) e[j] = __cosf(drowv * fr[j]);
        } else {
            #pragma unroll
            for (int j = 0; j < 8; ++j) e[j] = __sinf(drowv * fr[j]);
        }
        #pragma unroll
        for (int k = 0; k < 4; ++k) v[k] = pkh(e[2*k], e[2*k+1]);
    }
}

__global__ __launch_bounds__(512) void fused_kernel(
    const float* __restrict__ X, const float* __restrict__ atom_mask,
    const _Float16* __restrict__ wpad, const float* __restrict__ gamma,
    const float* __restrict__ beta, const int* __restrict__ idx_ws,
    float* __restrict__ out)
{
    __shared__ FusedSmem sm;
    const int t = threadIdx.x;
    const int row0 = blockIdx.x * MTILE;
    const int b = row0 / (LQ*KQ);            // tiles never straddle b (30720 % 128 == 0)

    if (t < MTILE) {
        int rg = row0 + t;
        int rem = rg - b*(LQ*KQ);
        int i = rem / KQ;
        int j = idx_ws[rg];
        sm.residg[t]       = b*LQ + i;
        sm.residg[MTILE+t] = b*LQ + j;
        sm.drow[t] = (float)j - (float)i;
    }
    if (t < EFQ) { sm.gsh[t] = gamma[t]; sm.bsh[t] = beta[t]; }
    __syncthreads();

    for (int u = t; u < 256*42; u += 512) {  // 21 exact iterations
        int s = u / 42; int e = u - s*42;
        sm.atoms[s*42 + e] = X[(size_t)sm.residg[s]*42 + e];
    }
    __syncthreads();

    if (t < 256) {
        float* at = &sm.atoms[t*42];
        float Nx=at[0],Ny=at[1],Nz=at[2], Cax=at[3],Cay=at[4],Caz=at[5],
              Cx=at[6],Cy=at[7],Cz=at[8];
        float bx=Cax-Nx, by=Cay-Ny, bz=Caz-Nz;
        float ex=Cx-Cax, ey=Cy-Cay, ez=Cz-Caz;
        float ax = by*ez - bz*ey, ay = bz*ex - bx*ez, az = bx*ey - by*ex;
        at[12] = -0.58273431f*ax + 0.56802827f*bx - 0.54067466f*ex + Cax;  // Cb
        at[13] = -0.58273431f*ay + 0.56802827f*by - 0.54067466f*ey + Cay;
        at[14] = -0.58273431f*az + 0.56802827f*bz - 0.54067466f*ez + Caz;
        unsigned mb = 0;
        const float* amp = &atom_mask[(size_t)sm.residg[t]*AQ];
        #pragma unroll
        for (int a = 0; a < AQ; ++a) if (amp[a] > 0.5f) mb |= (1u << a);
        sm.maskb[t] = mb;
    }

    const int w = t >> 6, lane = t & 63, q = lane >> 4, l15 = lane & 15;
    const int m = w*16 + l15;                 // tile-local row (0..127)

    // ---- loop-invariant hoists -------------------------------------------
    int boff0[8], boff1[8];                   // B-frag LDS offsets (XOR swizzle)
    #pragma unroll
    for (int nt = 0; nt < 8; ++nt) {
        int n = nt*16 + l15;
        boff0[nt] = n*64 + ((q ^ (n&7))*8);
        boff1[nt] = n*64 + (((4+q) ^ (n&7))*8);
    }
    int stRegion[2]; const _Float16* stBase[2];
    #pragma unroll
    for (int i2 = 0; i2 < 2; ++i2) {
        int region = w*2 + i2;                        // 16 regions x 8 rows
        int n = region*8 + (lane >> 3);
        int kbsrc = (lane & 7) ^ (lane >> 3);
        stRegion[i2] = region;
        stBase[i2] = wpad + (size_t)n*KPAD + kbsrc*8;
    }
    auto stage = [&](int c) {
        #pragma unroll
        for (int i2 = 0; i2 < 2; ++i2) {
            const _Float16* g = stBase[i2] + c*64;
            __builtin_amdgcn_global_load_lds(
                (const __attribute__((address_space(1))) uint32_t*)g,
                (__attribute__((address_space(3))) uint32_t*)&sm.Bl[stRegion[i2]*512],
                16, 0, 0);
        }
    };

    floatx4 acc[8];
    #pragma unroll
    for (int nt = 0; nt < 8; ++nt) acc[nt] = (floatx4){0.f,0.f,0.f,0.f};

    __syncthreads();                          // atoms/maskb ready

    const float* atomsA = &sm.atoms[m*42];
    const float* atomsB = &sm.atoms[(MTILE+m)*42];
    const unsigned maskA = sm.maskb[m], maskB = sm.maskb[MTILE+m];
    const float drowv = sm.drow[m];

    union H8 { uint32_t u[4]; half8 h; };
    for (int c = 0; c < NCHUNK; ++c) {
        if (c) __syncthreads();               // all reads of previous B chunk done
        stage(c);                             // async global->LDS, in flight during gen
        H8 va0, va1;
        gen8(atomsA, atomsB, maskA, maskB, drowv, c*64 + q*8,      va0.u);
        gen8(atomsA, atomsB, maskA, maskB, drowv, c*64 + 32 + q*8, va1.u);
        __syncthreads();                      // drains vmcnt: Bl ready
        #pragma unroll
        for (int nt = 0; nt < 8; ++nt) {
            half8 b0 = *reinterpret_cast<const half8*>(&sm.Bl[boff0[nt]]);
            half8 b1 = *reinterpret_cast<const half8*>(&sm.Bl[boff1[nt]]);
            acc[nt] = __builtin_amdgcn_mfma_f32_16x16x32_f16(va0.h, b0, acc[nt], 0, 0, 0);
            acc[nt] = __builtin_amdgcn_mfma_f32_16x16x32_f16(va1.h, b1, acc[nt], 0, 0, 0);
        }
    }

    // LayerNorm epilogue. C/D layout: col = lane&15, row = quad*4 + reg.
    #pragma unroll
    for (int v = 0; v < 4; ++v) {
        float s = 0.f, s2 = 0.f;
        #pragma unroll
        for (int nt = 0; nt < 8; ++nt) { float x = acc[nt][v]; s += x; s2 += x*x; }
        #pragma unroll
        for (int off = 1; off < 16; off <<= 1) {
            s  += __shfl_xor(s,  off);
            s2 += __shfl_xor(s2, off);
        }
        float mean = s * (1.0f/128.0f);
        float var  = s2 * (1.0f/128.0f) - mean*mean;
        float rstd = 1.0f / sqrtf(var + 1e-5f);
        int row_l = w*16 + q*4 + v;
        size_t obase = (size_t)(row0 + row_l)*EFQ;
        #pragma unroll
        for (int nt = 0; nt < 8; ++nt) {
            int col = nt*16 + l15;
            out[obase + col] = (acc[nt][v] - mean)*rstd*sm.gsh[col] + sm.bsh[col];
        }
    }
}

extern "C" void kernel_launch(void* const* d_in, const int* in_sizes, int n_in,
                              void* d_out, int out_size, void* d_ws, size_t ws_size,
                              hipStream_t stream)
{
    const float* X         = (const float*)d_in[0];
    const float* mask      = (const float*)d_in[1];
    // d_in[2] residue_idx, d_in[3] chain_labels: unused by the reference math
    const float* atom_mask = (const float*)d_in[4];
    const float* W         = (const float*)d_in[5];
    const float* gamma     = (const float*)d_in[6];
    const float* beta      = (const float*)d_in[7];
    float* out = (float*)d_out;

    int*       idx_ws = (int*)d_ws;                               // 61440*4 B
    _Float16*  wpad   = (_Float16*)((char*)d_ws + 262144);        // 128*3200*2 B

    hipLaunchKernelGGL(topk_kernel, dim3(306), dim3(512), 0, stream,
                       X, mask, W, out, idx_ws, wpad);
    hipLaunchKernelGGL(fused_kernel, dim3(ROWS/MTILE), dim3(512), 0, stream,
                       X, atom_mask, wpad, gamma, beta, idx_ws, out);
}

// Round 11
// 175.368 us; speedup vs baseline: 1.2909x; 1.0048x over previous
//
#include <hip/hip_runtime.h>
#include <hip/hip_bf16.h>
#include <stdint.h>

#define LQ 1024
#define BQ 2
#define AQ 14
#define KQ 30
#define EFQ 128
#define EDGE_IN 3152
#define KPAD 3200
#define NCHUNK 50
#define MTILE 128
#define ROWS (BQ*LQ*KQ)            /* 61440 */
#define EIDX_OFF (ROWS*EFQ)        /* 7864320 */

typedef __attribute__((ext_vector_type(8))) _Float16 half8;
typedef __attribute__((ext_vector_type(2))) _Float16 half2t;
typedef __attribute__((ext_vector_type(4))) float floatx4;
typedef unsigned long long ull;

static __device__ __forceinline__ uint32_t pkh(float a, float b) {
    auto h = __builtin_amdgcn_cvt_pkrtz(a, b);   // __fp16 ext_vector(2)
    return __builtin_bit_cast(uint32_t, h);
}
static __device__ __forceinline__ ull umin64(ull a, ull b) { return a < b ? a : b; }

// ---------------------------------------------------------------------------
// Kernel A v6 (unchanged from round 10 — measured ~2-10 µs): blocks 0..255
// topk (8 rows/block, one wave per row, u64-packed keys); blocks 256..305:
// W fp32 -> f16 padded copy.
// ---------------------------------------------------------------------------
__global__ __launch_bounds__(512) void topk_kernel(
    const float* __restrict__ X, const float* __restrict__ mask,
    const float* __restrict__ W, float* __restrict__ out,
    int* __restrict__ idx_ws, _Float16* __restrict__ wpad)
{
    __shared__ float xs[LQ], ys[LQ], zs[LQ], ms[LQ];
    const int t = threadIdx.x;

    if (blockIdx.x >= 256) {                    // ---- merged wpad ----
        int base = (blockIdx.x - 256)*8192 + t; // 50 blocks x 8192 = 409600 exact
        #pragma unroll
        for (int r = 0; r < 16; ++r) {
            int idx = base + r*512;
            int n = idx / KPAD, f = idx - n*KPAD;
            float v = (f < EDGE_IN) ? W[(size_t)n*EDGE_IN + f] : 0.0f;
            wpad[idx] = (_Float16)v;
        }
        return;
    }

    const int w = t >> 6, lane = t & 63;
    const int row = blockIdx.x*8 + w;           // same b for whole block
    const int b = row >> 10, i = row & (LQ - 1);

    for (int j = t; j < LQ; j += 512) {
        size_t base = ((size_t)(b*LQ + j))*42 + 3;   // atom 1 (CA)
        xs[j] = X[base+0]; ys[j] = X[base+1]; zs[j] = X[base+2];
        ms[j] = mask[b*LQ + j];
    }
    __syncthreads();

    const float mif = ms[i];
    const double cx = (double)xs[i], cy = (double)ys[i], cz = (double)zs[i];

    double Dk[16]; float mf[16];
    bool allone = (mif == 1.0f);
    #pragma unroll
    for (int s = 0; s < 16; ++s) {
        int j = s*64 + lane;
        double dx = __dsub_rn(cx, (double)xs[j]);
        double dy = __dsub_rn(cy, (double)ys[j]);
        double dz = __dsub_rn(cz, (double)zs[j]);
        mf[s] = ms[j];
        Dk[s] = __dadd_rn(__dadd_rn(__dmul_rn(dx,dx), __dmul_rn(dy,dy)),
                          __dmul_rn(dz,dz));
        allone = allone && (mf[s] == 1.0f);
    }

    if (!__all(allone ? 1 : 0)) {
        // exact general path: D = mi*mj*sqrt(ssq+1e-6); key = D + 2(1-m2)*max(D)
        const double mi_d = (double)mif;
        double lm = 0.0;
        #pragma unroll
        for (int s = 0; s < 16; ++s) {
            double m2 = __dmul_rn(mi_d, (double)mf[s]);
            Dk[s] = __dmul_rn(m2, sqrt(__dadd_rn(Dk[s], 1e-6)));
            lm = fmax(lm, Dk[s]);
        }
        #pragma unroll
        for (int off = 32; off; off >>= 1) lm = fmax(lm, __shfl_xor(lm, off));
        #pragma unroll
        for (int s = 0; s < 16; ++s) {
            double m2 = __dmul_rn(mi_d, (double)mf[s]);
            Dk[s] = __dadd_rn(Dk[s],
                    __dmul_rn(__dmul_rn(2.0, __dsub_rn(1.0, m2)), lm));
        }
    }

    ull key[16];
    #pragma unroll
    for (int s = 0; s < 16; ++s)
        key[s] = (((ull)__double_as_longlong(Dk[s])) & ~1023ull)
               | (unsigned)(s*64 + lane);

    for (int k = 0; k < KQ; ++k) {
        ull a0 = umin64(key[0],  key[1]),  a1 = umin64(key[2],  key[3]);
        ull a2 = umin64(key[4],  key[5]),  a3 = umin64(key[6],  key[7]);
        ull a4 = umin64(key[8],  key[9]),  a5 = umin64(key[10], key[11]);
        ull a6 = umin64(key[12], key[13]), a7 = umin64(key[14], key[15]);
        ull b0 = umin64(a0, a1), b1 = umin64(a2, a3);
        ull b2 = umin64(a4, a5), b3 = umin64(a6, a7);
        ull bk = umin64(umin64(b0, b1), umin64(b2, b3));
        #pragma unroll
        for (int off = 32; off; off >>= 1)
            bk = umin64(bk, (ull)__shfl_xor(bk, off));
        int j = (int)(bk & 1023ull);
        if (lane == 0) {
            int rg = row*KQ + k;
            idx_ws[rg] = j;
            out[EIDX_OFF + rg] = (float)j;
        }
        bool mine = ((j & 63) == lane);
        int s_win = j >> 6;
        #pragma unroll
        for (int s = 0; s < 16; ++s)
            key[s] = (mine && s == s_win) ? ~0ull : key[s];
    }
}

// ---------------------------------------------------------------------------
// Kernel B v7: fused feature-gen + f16 MFMA GEMM + LayerNorm.
// Atoms staged in LDS as PACKED F16 (x,y,z,pad per slot): LDS 63 -> 48.6 KB
// -> 3 blocks/CU (24 waves/CU) to cover the per-chunk barrier stalls.
// ---------------------------------------------------------------------------
struct FusedSmem {
    alignas(16) unsigned short atoms[256*56];  // f16 x,y,z,pad x 14 slots; 0..127 center, 128..255 neighbor
    alignas(16) unsigned short Bl[128*64];     // W chunk (f16 bits), XOR-swizzled
    alignas(16) float drow[MTILE];
    int residg[256];
    unsigned int maskb[256];
    float gsh[EFQ], bsh[EFQ];
};                                             // 48,640 B -> 3 blocks/CU

// Generate 8 contiguous features [f0, f0+8) for tile-local row m as 4 packed
// f16 dwords. RBF: exp(-((d - r*4/3)*0.8)^2) = exp2(-(u - r*v)^2),
// u = d*0.96089846, v = 1.28119795. Atom coords read as packed f16.
static __device__ __forceinline__ void gen8(
    const unsigned short* __restrict__ atomsA,
    const unsigned short* __restrict__ atomsB,
    unsigned maskA, unsigned maskB, float drowv,
    int f0, uint32_t* __restrict__ v)
{
    if (f0 >= 16) {
        int p = (f0 - 16) >> 4;
        if (p >= AQ*AQ) { v[0] = v[1] = v[2] = v[3] = 0u; return; }
        int rbase = (f0 - 16) & 15;                 // 0 or 8
        int a  = (p * 74899) >> 20;                 // p / 14 for p < 2048
        int bp = p - a*14;
        bool czero = ((((maskA >> a) | (maskB >> bp)) & 1u) != 0u);
        half2t c0 = *reinterpret_cast<const half2t*>(atomsA + a*4);
        half2t c1 = *reinterpret_cast<const half2t*>(atomsA + a*4 + 2);
        half2t n0 = *reinterpret_cast<const half2t*>(atomsB + bp*4);
        half2t n1 = *reinterpret_cast<const half2t*>(atomsB + bp*4 + 2);
        half2t dxy = c0 - n0;                        // v_pk_add_f16
        half2t dzw = c1 - n1;
        float dx = (float)dxy[0], dy = (float)dxy[1], dz = (float)dzw[0];
        float u = __builtin_amdgcn_sqrtf(dx*dx + dy*dy + dz*dz + 1e-6f) * 0.96089846f;
        float e[8];
        #pragma unroll
        for (int j = 0; j < 8; ++j) {
            float tt = __fmaf_rn(-(float)(rbase + j), 1.28119795f, u);
            e[j] = __builtin_amdgcn_exp2f(-(tt*tt));
        }
        #pragma unroll
        for (int k = 0; k < 4; ++k) v[k] = czero ? 0u : pkh(e[2*k], e[2*k+1]);
    } else {
        const float fr[8] = {1.0f, 0.31622776601683794f, 0.1f,
            0.031622776601683794f, 0.01f, 0.0031622776601683794f,
            0.001f, 0.00031622776601683794f};
        float e[8];
        if (f0 == 0) {
            #pragma unroll
            for (int j = 0; j < 8; ++j) e[j] = __cosf(drowv * fr[j]);
        } else {
            #pragma unroll
            for (int j = 0; j < 8; ++j) e[j] = __sinf(drowv * fr[j]);
        }
        #pragma unroll
        for (int k = 0; k < 4; ++k) v[k] = pkh(e[2*k], e[2*k+1]);
    }
}

__global__ __launch_bounds__(512) void fused_kernel(
    const float* __restrict__ X, const float* __restrict__ atom_mask,
    const _Float16* __restrict__ wpad, const float* __restrict__ gamma,
    const float* __restrict__ beta, const int* __restrict__ idx_ws,
    float* __restrict__ out)
{
    __shared__ FusedSmem sm;
    const int t = threadIdx.x;
    const int row0 = blockIdx.x * MTILE;
    const int b = row0 / (LQ*KQ);            // tiles never straddle b (30720 % 128 == 0)

    if (t < MTILE) {
        int rg = row0 + t;
        int rem = rg - b*(LQ*KQ);
        int i = rem / KQ;
        int j = idx_ws[rg];
        sm.residg[t]       = b*LQ + i;
        sm.residg[MTILE+t] = b*LQ + j;
        sm.drow[t] = (float)j - (float)i;
    }
    if (t < EFQ) { sm.gsh[t] = gamma[t]; sm.bsh[t] = beta[t]; }
    __syncthreads();

    // stage atoms: fp32 global -> packed f16 LDS (x,y,z,0 per slot)
    for (int u = t; u < 256*14; u += 512) {  // 7 exact iterations
        int s = u / 14; int a = u - s*14;
        const float* xp = X + (size_t)sm.residg[s]*42 + a*3;
        uint2 pk; pk.x = pkh(xp[0], xp[1]); pk.y = pkh(xp[2], 0.0f);
        *reinterpret_cast<uint2*>(&sm.atoms[s*56 + a*4]) = pk;
    }
    __syncthreads();

    if (t < 256) {
        unsigned short* at = &sm.atoms[t*56];
        auto ld3 = [&](int slot, float& x, float& y, float& z) {
            half2t p0 = *reinterpret_cast<const half2t*>(at + slot*4);
            half2t p1 = *reinterpret_cast<const half2t*>(at + slot*4 + 2);
            x = (float)p0[0]; y = (float)p0[1]; z = (float)p1[0];
        };
        float Nx,Ny,Nz, Cax,Cay,Caz, Cx,Cy,Cz;
        ld3(0, Nx,Ny,Nz); ld3(1, Cax,Cay,Caz); ld3(2, Cx,Cy,Cz);
        float bx=Cax-Nx, by=Cay-Ny, bz=Caz-Nz;
        float ex=Cx-Cax, ey=Cy-Cay, ez=Cz-Caz;
        float ax = by*ez - bz*ey, ay = bz*ex - bx*ez, az = bx*ey - by*ex;
        float cbx = -0.58273431f*ax + 0.56802827f*bx - 0.54067466f*ex + Cax;
        float cby = -0.58273431f*ay + 0.56802827f*by - 0.54067466f*ey + Cay;
        float cbz = -0.58273431f*az + 0.56802827f*bz - 0.54067466f*ez + Caz;
        uint2 pk; pk.x = pkh(cbx, cby); pk.y = pkh(cbz, 0.0f);
        *reinterpret_cast<uint2*>(at + 4*4) = pk;    // slot 4 = Cb
        unsigned mb = 0;
        const float* amp = &atom_mask[(size_t)sm.residg[t]*AQ];
        #pragma unroll
        for (int a = 0; a < AQ; ++a) if (amp[a] > 0.5f) mb |= (1u << a);
        sm.maskb[t] = mb;
    }

    const int w = t >> 6, lane = t & 63, q = lane >> 4, l15 = lane & 15;
    const int m = w*16 + l15;                 // tile-local row (0..127)

    // ---- loop-invariant hoists -------------------------------------------
    int boff0[8], boff1[8];                   // B-frag LDS offsets (XOR swizzle)
    #pragma unroll
    for (int nt = 0; nt < 8; ++nt) {
        int n = nt*16 + l15;
        boff0[nt] = n*64 + ((q ^ (n&7))*8);
        boff1[nt] = n*64 + (((4+q) ^ (n&7))*8);
    }
    int stRegion[2]; const _Float16* stBase[2];
    #pragma unroll
    for (int i2 = 0; i2 < 2; ++i2) {
        int region = w*2 + i2;                        // 16 regions x 8 rows
        int n = region*8 + (lane >> 3);
        int kbsrc = (lane & 7) ^ (lane >> 3);
        stRegion[i2] = region;
        stBase[i2] = wpad + (size_t)n*KPAD + kbsrc*8;
    }
    auto stage = [&](int c) {
        #pragma unroll
        for (int i2 = 0; i2 < 2; ++i2) {
            const _Float16* g = stBase[i2] + c*64;
            __builtin_amdgcn_global_load_lds(
                (const __attribute__((address_space(1))) uint32_t*)g,
                (__attribute__((address_space(3))) uint32_t*)&sm.Bl[stRegion[i2]*512],
                16, 0, 0);
        }
    };

    floatx4 acc[8];
    #pragma unroll
    for (int nt = 0; nt < 8; ++nt) acc[nt] = (floatx4){0.f,0.f,0.f,0.f};

    __syncthreads();                          // atoms/maskb ready

    const unsigned short* atomsA = &sm.atoms[m*56];
    const unsigned short* atomsB = &sm.atoms[(MTILE+m)*56];
    const unsigned maskA = sm.maskb[m], maskB = sm.maskb[MTILE+m];
    const float drowv = sm.drow[m];

    union H8 { uint32_t u[4]; half8 h; };
    for (int c = 0; c < NCHUNK; ++c) {
        if (c) __syncthreads();               // all reads of previous B chunk done
        stage(c);                             // async global->LDS, in flight during gen
        H8 va0, va1;
        gen8(atomsA, atomsB, maskA, maskB, drowv, c*64 + q*8,      va0.u);
        gen8(atomsA, atomsB, maskA, maskB, drowv, c*64 + 32 + q*8, va1.u);
        __syncthreads();                      // drains vmcnt: Bl ready
        #pragma unroll
        for (int nt = 0; nt < 8; ++nt) {
            half8 b0 = *reinterpret_cast<const half8*>(&sm.Bl[boff0[nt]]);
            half8 b1 = *reinterpret_cast<const half8*>(&sm.Bl[boff1[nt]]);
            acc[nt] = __builtin_amdgcn_mfma_f32_16x16x32_f16(va0.h, b0, acc[nt], 0, 0, 0);
            acc[nt] = __builtin_amdgcn_mfma_f32_16x16x32_f16(va1.h, b1, acc[nt], 0, 0, 0);
        }
    }

    // LayerNorm epilogue. C/D layout: col = lane&15, row = quad*4 + reg.
    #pragma unroll
    for (int v = 0; v < 4; ++v) {
        float s = 0.f, s2 = 0.f;
        #pragma unroll
        for (int nt = 0; nt < 8; ++nt) { float x = acc[nt][v]; s += x; s2 += x*x; }
        #pragma unroll
        for (int off = 1; off < 16; off <<= 1) {
            s  += __shfl_xor(s,  off);
            s2 += __shfl_xor(s2, off);
        }
        float mean = s * (1.0f/128.0f);
        float var  = s2 * (1.0f/128.0f) - mean*mean;
        float rstd = 1.0f / sqrtf(var + 1e-5f);
        int row_l = w*16 + q*4 + v;
        size_t obase = (size_t)(row0 + row_l)*EFQ;
        #pragma unroll
        for (int nt = 0; nt < 8; ++nt) {
            int col = nt*16 + l15;
            out[obase + col] = (acc[nt][v] - mean)*rstd*sm.gsh[col] + sm.bsh[col];
        }
    }
}

extern "C" void kernel_launch(void* const* d_in, const int* in_sizes, int n_in,
                              void* d_out, int out_size, void* d_ws, size_t ws_size,
                              hipStream_t stream)
{
    const float* X         = (const float*)d_in[0];
    const float* mask      = (const float*)d_in[1];
    // d_in[2] residue_idx, d_in[3] chain_labels: unused by the reference math
    const float* atom_mask = (const float*)d_in[4];
    const float* W         = (const float*)d_in[5];
    const float* gamma     = (const float*)d_in[6];
    const float* beta      = (const float*)d_in[7];
    float* out = (float*)d_out;

    int*       idx_ws = (int*)d_ws;                               // 61440*4 B
    _Float16*  wpad   = (_Float16*)((char*)d_ws + 262144);        // 128*3200*2 B

    hipLaunchKernelGGL(topk_kernel, dim3(306), dim3(512), 0, stream,
                       X, mask, W, out, idx_ws, wpad);
    hipLaunchKernelGGL(fused_kernel, dim3(ROWS/MTILE), dim3(512), 0, stream,
                       X, atom_mask, wpad, gamma, beta, idx_ws, out);
}